// Round 7
// baseline (2379.056 us; speedup 1.0000x reference)
//
#include <hip/hip_runtime.h>
#include <hip/hip_bf16.h>

typedef __bf16 bf16;
typedef _Float16 fp16;
typedef __attribute__((ext_vector_type(8))) __bf16 bf16x8;
typedef __attribute__((ext_vector_type(2))) _Float16 fp16x2;
typedef __attribute__((ext_vector_type(4))) float f32x4;

#define H_IN 1342
#define TT   128
#define BB   128

static __device__ __forceinline__ f32x4 mfma16(bf16x8 a, bf16x8 b, f32x4 c) {
    return __builtin_amdgcn_mfma_f32_16x16x32_bf16(a, b, c, 0, 0, 0);
}
static __device__ __forceinline__ float sigf(float x) {
    return 1.f / (1.f + __expf(-x));
}
static __device__ __forceinline__ float tanhfast(float x) {
    return 2.f / (1.f + __expf(-2.f * x)) - 1.f;
}

// ---------------------------------------------------------------------------
// Pack the three w_hh matrices (768x256) into MFMA B-fragment order.
// layer l at Wh + l*196608; frag f = nt*8+kt; elem (lane,j) =
// w_hh[nt*16+(lane&15)][kt*32+(lane>>4)*8+j].   (round-6 verified)
// ---------------------------------------------------------------------------
__global__ void prep_pack2(const float* __restrict__ whh0,
                           const float* __restrict__ whh1,
                           const float* __restrict__ whh2,
                           bf16* __restrict__ Wh)
{
    int idx = blockIdx.x * blockDim.x + threadIdx.x;
    if (idx < 589824) {
        int l = idx / 196608;
        int r = idx - l * 196608;
        const float* w = (l == 0) ? whh0 : (l == 1) ? whh1 : whh2;
        int f = r >> 9, q = r & 511;
        int lane = q >> 3, j = q & 7;
        int nt = f >> 3, kt = f & 7;
        int n = nt * 16 + (lane & 15);
        int k = kt * 32 + (lane >> 4) * 8 + j;
        Wh[idx] = (bf16)w[n * 256 + k];
    }
}

// ---------------------------------------------------------------------------
// Layer-0 input GEMM. Epilogue: r,z -> interleaved fp16x2 plane gxrz2
// (dword per (row, c): lo=r, hi=z, c in [0,256)), n -> fp32 plane gxn.
// b_hh folded into r,z. Rows of X-as-matrix are b*128+t (round-6 verified).
// ---------------------------------------------------------------------------
__global__ __launch_bounds__(512) void gemm_gx0(const float* __restrict__ X,
                                                const float* __restrict__ W,
                                                const float* __restrict__ bih,
                                                const float* __restrict__ bhh,
                                                char*  __restrict__ gxrz2b,
                                                float* __restrict__ gxn)
{
    __shared__ bf16 As[128][40];
    __shared__ bf16 Bs[256][40];
    const int tid  = threadIdx.x;
    const int lane = tid & 63;
    const int w    = tid >> 6;
    const int cl   = lane & 15;
    const int lh   = lane >> 4;
    const int rm0  = blockIdx.x * 128;
    const int n0   = blockIdx.y * 256;

    f32x4 acc[16];
#pragma unroll
    for (int i = 0; i < 16; ++i) acc[i] = (f32x4){0.f, 0.f, 0.f, 0.f};

    for (int kt = 0; kt < 42; ++kt) {
        const int k0 = kt * 32;
        {
            int row = tid >> 2;
            int c   = (tid & 3) * 8;
            const float* src = X + (size_t)(rm0 + row) * H_IN + (k0 + c);
            bf16x8 pk;
            if (k0 + c + 8 <= H_IN) {
                const float2* s2 = (const float2*)src;
                float2 v0 = s2[0], v1 = s2[1], v2 = s2[2], v3 = s2[3];
                pk[0] = (bf16)v0.x; pk[1] = (bf16)v0.y; pk[2] = (bf16)v1.x; pk[3] = (bf16)v1.y;
                pk[4] = (bf16)v2.x; pk[5] = (bf16)v2.y; pk[6] = (bf16)v3.x; pk[7] = (bf16)v3.y;
            } else {
#pragma unroll
                for (int i = 0; i < 8; ++i)
                    pk[i] = (bf16)((k0 + c + i < H_IN) ? src[i] : 0.f);
            }
            *(bf16x8*)&As[row][c] = pk;
        }
        {
            int row = tid >> 1;
            int c   = (tid & 1) * 16;
            const float* src = W + (size_t)(n0 + row) * H_IN + (k0 + c);
#pragma unroll
            for (int h = 0; h < 2; ++h) {
                const float* s = src + h * 8;
                bf16x8 pk;
                if (k0 + c + h * 8 + 8 <= H_IN) {
                    const float2* s2 = (const float2*)s;
                    float2 v0 = s2[0], v1 = s2[1], v2 = s2[2], v3 = s2[3];
                    pk[0] = (bf16)v0.x; pk[1] = (bf16)v0.y; pk[2] = (bf16)v1.x; pk[3] = (bf16)v1.y;
                    pk[4] = (bf16)v2.x; pk[5] = (bf16)v2.y; pk[6] = (bf16)v3.x; pk[7] = (bf16)v3.y;
                } else {
#pragma unroll
                    for (int i = 0; i < 8; ++i)
                        pk[i] = (bf16)((k0 + c + h * 8 + i < H_IN) ? s[i] : 0.f);
                }
                *(bf16x8*)&Bs[row][c + h * 8] = pk;
            }
        }
        __syncthreads();
        bf16x8 a = *(const bf16x8*)&As[w * 16 + cl][lh * 8];
#pragma unroll
        for (int nt = 0; nt < 16; ++nt) {
            bf16x8 b = *(const bf16x8*)&Bs[nt * 16 + cl][lh * 8];
            acc[nt] = mfma16(a, b, acc[nt]);
        }
        __syncthreads();
    }
#pragma unroll
    for (int nt = 0; nt < 16; ++nt) {
#pragma unroll
        for (int r = 0; r < 4; ++r) {
            int rm  = rm0 + w * 16 + 4 * lh + r;
            int col = n0 + nt * 16 + cl;
            int b = rm >> 7, t = rm & 127;          // X rows are b*128+t
            size_t ro = (size_t)t * BB + b;
            if (col < 512) {
                float v = acc[nt][r] + bih[col] + bhh[col];
                *(fp16*)(gxrz2b + ro * 1024 + (col & 255) * 4 + (col >> 8) * 2) = (fp16)v;
            } else {
                gxn[ro * 256 + (col - 512)] = acc[nt][r] + bih[col];
            }
        }
    }
}

// ---------------------------------------------------------------------------
// Layers 1/2 input GEMM: same epilogue; A = Y bf16 [t*128+b][256].
// ---------------------------------------------------------------------------
__global__ __launch_bounds__(512) void gemm_gxy(const bf16* __restrict__ Y,
                                                const float* __restrict__ W,
                                                const float* __restrict__ bih,
                                                const float* __restrict__ bhh,
                                                char*  __restrict__ gxrz2b,
                                                float* __restrict__ gxn)
{
    __shared__ bf16 As[128][40];
    __shared__ bf16 Bs[256][40];
    const int tid  = threadIdx.x;
    const int lane = tid & 63;
    const int w    = tid >> 6;
    const int cl   = lane & 15;
    const int lh   = lane >> 4;
    const int rm0  = blockIdx.x * 128;
    const int n0   = blockIdx.y * 256;

    f32x4 acc[16];
#pragma unroll
    for (int i = 0; i < 16; ++i) acc[i] = (f32x4){0.f, 0.f, 0.f, 0.f};

    for (int kt = 0; kt < 8; ++kt) {
        const int k0 = kt * 32;
        {
            int row = tid >> 2;
            int c   = (tid & 3) * 8;
            *(bf16x8*)&As[row][c] =
                *(const bf16x8*)(Y + (size_t)(rm0 + row) * 256 + k0 + c);
        }
        {
            int row = tid >> 1;
            int c   = (tid & 1) * 16;
            const float* src = W + (size_t)(n0 + row) * 256 + (k0 + c);
#pragma unroll
            for (int h = 0; h < 2; ++h) {
                const float2* s2 = (const float2*)(src + h * 8);
                float2 v0 = s2[0], v1 = s2[1], v2 = s2[2], v3 = s2[3];
                bf16x8 pk;
                pk[0] = (bf16)v0.x; pk[1] = (bf16)v0.y; pk[2] = (bf16)v1.x; pk[3] = (bf16)v1.y;
                pk[4] = (bf16)v2.x; pk[5] = (bf16)v2.y; pk[6] = (bf16)v3.x; pk[7] = (bf16)v3.y;
                *(bf16x8*)&Bs[row][c + h * 8] = pk;
            }
        }
        __syncthreads();
        bf16x8 a = *(const bf16x8*)&As[w * 16 + cl][lh * 8];
#pragma unroll
        for (int nt = 0; nt < 16; ++nt) {
            bf16x8 b = *(const bf16x8*)&Bs[nt * 16 + cl][lh * 8];
            acc[nt] = mfma16(a, b, acc[nt]);
        }
        __syncthreads();
    }
#pragma unroll
    for (int nt = 0; nt < 16; ++nt) {
#pragma unroll
        for (int r = 0; r < 4; ++r) {
            size_t rm = (size_t)(rm0 + w * 16 + 4 * lh + r);   // = t*128 + b
            int col = n0 + nt * 16 + cl;
            if (col < 512) {
                float v = acc[nt][r] + bih[col] + bhh[col];
                *(fp16*)(gxrz2b + rm * 1024 + (col & 255) * 4 + (col >> 8) * 2) = (fp16)v;
            } else {
                gxn[rm * 256 + (col - 512)] = acc[nt][r] + bih[col];
            }
        }
    }
}

// ---------------------------------------------------------------------------
// Recurrent layer kernel v2: 8 blocks x 256 threads (4 waves, 1 wave/SIMD,
// 512-VGPR budget). Wave w owns col-tiles jt = 4w..4w+3; ALL 96 B-fragments
// resident in registers for the whole T loop. Raw s_barrier (lgkm-only
// drain) keeps Y/hnf stores and gx prefetch in flight across barriers.
// fp32 h carry lives in LDS hp[][]; bf16 h in Ah[][] feeds MFMA.
// ---------------------------------------------------------------------------
__global__ __launch_bounds__(256, 1) void gru_rec(
    const unsigned int* __restrict__ grzp,  // [T*B][256] dwords: (fp16 r, fp16 z)
    const float* __restrict__ gxn,          // [T*B][256] fp32 (n, incl b_ih)
    const bf16*  __restrict__ Wh,           // this layer's hh pack
    const float* __restrict__ bhh,          // raw b_hh (768); only n-part used
    const float* __restrict__ h0,           // hidden + l*128*256
    bf16*  __restrict__ Y,                  // [T*B][256] bf16 out (or null)
    float* __restrict__ hnfL)               // hnf + l*256 (stride 768)
{
    __shared__ bf16  Ah[16][264];
    __shared__ float hp[16][260];
    const int tid  = threadIdx.x;           // 0..255
    const int lane = tid & 63;
    const int w    = tid >> 6;              // 0..3
    const int cl   = lane & 15;
    const int lh   = lane >> 4;
    const int g    = blockIdx.x;

    // ---- all 96 B-fragments -> registers ----
    bf16x8 Br[4][8], Bz[4][8], Bn[4][8];
#pragma unroll
    for (int ji = 0; ji < 4; ++ji) {
        const int jt = w * 4 + ji;
#pragma unroll
        for (int kk = 0; kk < 8; ++kk) {
            Br[ji][kk] = *(const bf16x8*)(Wh + (size_t)(( jt       * 8 + kk) * 512) + lane * 8);
            Bz[ji][kk] = *(const bf16x8*)(Wh + (size_t)(((16 + jt) * 8 + kk) * 512) + lane * 8);
            Bn[ji][kk] = *(const bf16x8*)(Wh + (size_t)(((32 + jt) * 8 + kk) * 512) + lane * 8);
        }
    }
    float bN[4];
#pragma unroll
    for (int ji = 0; ji < 4; ++ji)
        bN[ji] = bhh[512 + (w * 4 + ji) * 16 + cl];

    // ---- stage h0 (fp32 master in hp, bf16 in Ah) + gx(0) prefetch ----
    unsigned int grz[4][4];
    float        gnr[4][4];
#pragma unroll
    for (int ji = 0; ji < 4; ++ji) {
        const int col = (w * 4 + ji) * 16 + cl;
#pragma unroll
        for (int r = 0; r < 4; ++r) {
            const int m = 4 * lh + r;
            float v = h0[(size_t)(g * 16 + m) * 256 + col];
            hp[m][col] = v;
            Ah[m][col] = (bf16)v;
            const size_t ro = (size_t)(g * 16 + m);   // t=0
            grz[ji][r] = grzp[ro * 256 + col];
            gnr[ji][r] = gxn [ro * 256 + col];
        }
    }
    __syncthreads();   // one-time full drain: gx(0) in regs, LDS staged

    for (int t = 0; t < TT; ++t) {
        // ---- MFMA phase (weights in regs; A from LDS) ----
        f32x4 cr[4], cz[4], cn[4];
#pragma unroll
        for (int i = 0; i < 4; ++i) {
            cr[i] = (f32x4){0.f,0.f,0.f,0.f};
            cz[i] = (f32x4){0.f,0.f,0.f,0.f};
            cn[i] = (f32x4){0.f,0.f,0.f,0.f};
        }
#pragma unroll
        for (int kk = 0; kk < 8; ++kk) {
            bf16x8 a = *(const bf16x8*)&Ah[cl][kk * 32 + lh * 8];
#pragma unroll
            for (int ji = 0; ji < 4; ++ji) {
                cr[ji] = mfma16(a, Br[ji][kk], cr[ji]);
                cz[ji] = mfma16(a, Bz[ji][kk], cz[ji]);
                cn[ji] = mfma16(a, Bn[ji][kk], cn[ji]);
            }
        }
        asm volatile("s_waitcnt lgkmcnt(0)" ::: "memory");
        __builtin_amdgcn_sched_barrier(0);
        __builtin_amdgcn_s_barrier();          // A: all waves done reading Ah
        __builtin_amdgcn_sched_barrier(0);

        // ---- gates: consume gx(t) regs, write h, prefetch gx(t+1) ----
        const int tn = (t + 1 < TT) ? (t + 1) : t;
#pragma unroll
        for (int ji = 0; ji < 4; ++ji) {
            const int col = (w * 4 + ji) * 16 + cl;
#pragma unroll
            for (int r = 0; r < 4; ++r) {
                const int m = 4 * lh + r;
                fp16x2 rz = __builtin_bit_cast(fp16x2, grz[ji][r]);
                float hv = hp[m][col];
                float rr_ = sigf((float)rz[0] + cr[ji][r]);
                float zz  = sigf((float)rz[1] + cz[ji][r]);
                float nn  = tanhfast(gnr[ji][r] + rr_ * (cn[ji][r] + bN[ji]));
                float hnew = (1.f - zz) * nn + zz * hv;
                hp[m][col] = hnew;
                Ah[m][col] = (bf16)hnew;
                if (Y) Y[((size_t)t * BB + g * 16 + m) * 256 + col] = (bf16)hnew;
                if (t == TT - 1) hnfL[(size_t)(g * 16 + m) * 768 + col] = hnew;
                // prefetch next step's gx into the just-freed regs
                const size_t ro = (size_t)tn * BB + g * 16 + m;
                grz[ji][r] = grzp[ro * 256 + col];
                gnr[ji][r] = gxn [ro * 256 + col];
            }
        }
        asm volatile("s_waitcnt lgkmcnt(0)" ::: "memory");
        __builtin_amdgcn_sched_barrier(0);
        __builtin_amdgcn_s_barrier();          // B: Ah writes visible
        __builtin_amdgcn_sched_barrier(0);
    }
}

// ---------------------------------------------------------------------------
__global__ __launch_bounds__(256) void fc_out(const float* __restrict__ hn,
                                              const float* __restrict__ fcw,
                                              const float* __restrict__ fcb,
                                              float* __restrict__ out)
{
    __shared__ float hs[768];
    const int b = blockIdx.x;
    for (int i = threadIdx.x; i < 768; i += 256) hs[i] = hn[(size_t)b * 768 + i];
    __syncthreads();
    for (int i = threadIdx.x; i < H_IN; i += 256) {
        const float4* wr = (const float4*)(fcw + (size_t)i * 768);
        float a0 = 0.f, a1 = 0.f, a2 = 0.f, a3 = 0.f;
#pragma unroll 4
        for (int c = 0; c < 192; ++c) {
            float4 wv = wr[c];
            const float* h4 = &hs[c * 4];
            a0 += wv.x * h4[0]; a1 += wv.y * h4[1];
            a2 += wv.z * h4[2]; a3 += wv.w * h4[3];
        }
        out[(size_t)b * H_IN + i] = fcb[i] + a0 + a1 + a2 + a3;
    }
}

extern "C" void kernel_launch(void* const* d_in, const int* in_sizes, int n_in,
                              void* d_out, int out_size, void* d_ws, size_t ws_size,
                              hipStream_t stream) {
    const float* X    = (const float*)d_in[0];
    const float* hid  = (const float*)d_in[1];
    const float* wih0 = (const float*)d_in[2];
    const float* whh0 = (const float*)d_in[3];
    const float* bih0 = (const float*)d_in[4];
    const float* bhh0 = (const float*)d_in[5];
    const float* wih1 = (const float*)d_in[6];
    const float* whh1 = (const float*)d_in[7];
    const float* bih1 = (const float*)d_in[8];
    const float* bhh1 = (const float*)d_in[9];
    const float* wih2 = (const float*)d_in[10];
    const float* whh2 = (const float*)d_in[11];
    const float* bih2 = (const float*)d_in[12];
    const float* bhh2 = (const float*)d_in[13];
    const float* fcw  = (const float*)d_in[14];
    const float* fcb  = (const float*)d_in[15];
    float* out = (float*)d_out;

    // Layout (total 43,525,120 B — within the known-safe 52.7 MB):
    char* ws = (char*)d_ws;
    bf16*  Wh    = (bf16*)ws;                      //          0 .. 1,179,648
    float* hnf   = (float*)(ws + 1188864);         //  1,188,864 .. 1,582,080
    bf16*  Y     = (bf16*)(ws + 1582080);          //  1,582,080 .. 9,970,688
    float* gxn   = (float*)(ws + 9970688);         //  9,970,688 .. 26,747,904
    char*  gxrzb = ws + 26747904;                  // 26,747,904 .. 43,525,120
    const unsigned int* grzp = (const unsigned int*)gxrzb;

    prep_pack2<<<dim3(1152), dim3(512), 0, stream>>>(whh0, whh1, whh2, Wh);
    // layer 0
    gemm_gx0<<<dim3(128, 3), dim3(512), 0, stream>>>(X, wih0, bih0, bhh0, gxrzb, gxn);
    gru_rec<<<dim3(8), dim3(256), 0, stream>>>(grzp, gxn, Wh, bhh0,
                                               hid, Y, hnf);
    // layer 1
    gemm_gxy<<<dim3(128, 3), dim3(512), 0, stream>>>(Y, wih1, bih1, bhh1, gxrzb, gxn);
    gru_rec<<<dim3(8), dim3(256), 0, stream>>>(grzp, gxn, Wh + 196608, bhh1,
                                               hid + 32768, Y, hnf + 256);
    // layer 2
    gemm_gxy<<<dim3(128, 3), dim3(512), 0, stream>>>(Y, wih2, bih2, bhh2, gxrzb, gxn);
    gru_rec<<<dim3(8), dim3(256), 0, stream>>>(grzp, gxn, Wh + 393216, bhh2,
                                               hid + 65536, (bf16*)nullptr, hnf + 512);
    // head
    fc_out<<<dim3(128), dim3(256), 0, stream>>>(hnf, fcw, fcb, out);
    hipMemcpyAsync(out + 171776, hid, 98304 * sizeof(float),
                   hipMemcpyDeviceToDevice, stream);
}

// Round 8
// 1809.804 us; speedup vs baseline: 1.3145x; 1.3145x over previous
//
#include <hip/hip_runtime.h>
#include <hip/hip_bf16.h>

typedef __bf16 bf16;
typedef _Float16 fp16;
typedef __attribute__((ext_vector_type(8))) __bf16 bf16x8;
typedef __attribute__((ext_vector_type(2))) _Float16 fp16x2;
typedef __attribute__((ext_vector_type(4))) float f32x4;

#define H_IN 1342
#define TT   128
#define BB   128

static __device__ __forceinline__ f32x4 mfma16(bf16x8 a, bf16x8 b, f32x4 c) {
    return __builtin_amdgcn_mfma_f32_16x16x32_bf16(a, b, c, 0, 0, 0);
}
static __device__ __forceinline__ float sigf(float x) {
    return 1.f / (1.f + __expf(-x));
}
static __device__ __forceinline__ float tanhfast(float x) {
    return 2.f / (1.f + __expf(-2.f * x)) - 1.f;
}

// ---------------------------------------------------------------------------
// Pack the three w_hh matrices (768x256) into MFMA B-fragment order.
// (round-6 verified)
// ---------------------------------------------------------------------------
__global__ void prep_pack2(const float* __restrict__ whh0,
                           const float* __restrict__ whh1,
                           const float* __restrict__ whh2,
                           bf16* __restrict__ Wh)
{
    int idx = blockIdx.x * blockDim.x + threadIdx.x;
    if (idx < 589824) {
        int l = idx / 196608;
        int r = idx - l * 196608;
        const float* w = (l == 0) ? whh0 : (l == 1) ? whh1 : whh2;
        int f = r >> 9, q = r & 511;
        int lane = q >> 3, j = q & 7;
        int nt = f >> 3, kt = f & 7;
        int n = nt * 16 + (lane & 15);
        int k = kt * 32 + (lane >> 4) * 8 + j;
        Wh[idx] = (bf16)w[n * 256 + k];
    }
}

// ---------------------------------------------------------------------------
// Layer-0 input GEMM. Epilogue: r,z -> interleaved fp16x2 dword plane
// (lo=r, hi=z, b_hh folded), n -> fp32 plane. (round-6/7 verified)
// ---------------------------------------------------------------------------
__global__ __launch_bounds__(512) void gemm_gx0(const float* __restrict__ X,
                                                const float* __restrict__ W,
                                                const float* __restrict__ bih,
                                                const float* __restrict__ bhh,
                                                char*  __restrict__ gxrz2b,
                                                float* __restrict__ gxn)
{
    __shared__ bf16 As[128][40];
    __shared__ bf16 Bs[256][40];
    const int tid  = threadIdx.x;
    const int lane = tid & 63;
    const int w    = tid >> 6;
    const int cl   = lane & 15;
    const int lh   = lane >> 4;
    const int rm0  = blockIdx.x * 128;
    const int n0   = blockIdx.y * 256;

    f32x4 acc[16];
#pragma unroll
    for (int i = 0; i < 16; ++i) acc[i] = (f32x4){0.f, 0.f, 0.f, 0.f};

    for (int kt = 0; kt < 42; ++kt) {
        const int k0 = kt * 32;
        {
            int row = tid >> 2;
            int c   = (tid & 3) * 8;
            const float* src = X + (size_t)(rm0 + row) * H_IN + (k0 + c);
            bf16x8 pk;
            if (k0 + c + 8 <= H_IN) {
                const float2* s2 = (const float2*)src;
                float2 v0 = s2[0], v1 = s2[1], v2 = s2[2], v3 = s2[3];
                pk[0] = (bf16)v0.x; pk[1] = (bf16)v0.y; pk[2] = (bf16)v1.x; pk[3] = (bf16)v1.y;
                pk[4] = (bf16)v2.x; pk[5] = (bf16)v2.y; pk[6] = (bf16)v3.x; pk[7] = (bf16)v3.y;
            } else {
#pragma unroll
                for (int i = 0; i < 8; ++i)
                    pk[i] = (bf16)((k0 + c + i < H_IN) ? src[i] : 0.f);
            }
            *(bf16x8*)&As[row][c] = pk;
        }
        {
            int row = tid >> 1;
            int c   = (tid & 1) * 16;
            const float* src = W + (size_t)(n0 + row) * H_IN + (k0 + c);
#pragma unroll
            for (int h = 0; h < 2; ++h) {
                const float* s = src + h * 8;
                bf16x8 pk;
                if (k0 + c + h * 8 + 8 <= H_IN) {
                    const float2* s2 = (const float2*)s;
                    float2 v0 = s2[0], v1 = s2[1], v2 = s2[2], v3 = s2[3];
                    pk[0] = (bf16)v0.x; pk[1] = (bf16)v0.y; pk[2] = (bf16)v1.x; pk[3] = (bf16)v1.y;
                    pk[4] = (bf16)v2.x; pk[5] = (bf16)v2.y; pk[6] = (bf16)v3.x; pk[7] = (bf16)v3.y;
                } else {
#pragma unroll
                    for (int i = 0; i < 8; ++i)
                        pk[i] = (bf16)((k0 + c + h * 8 + i < H_IN) ? s[i] : 0.f);
                }
                *(bf16x8*)&Bs[row][c + h * 8] = pk;
            }
        }
        __syncthreads();
        bf16x8 a = *(const bf16x8*)&As[w * 16 + cl][lh * 8];
#pragma unroll
        for (int nt = 0; nt < 16; ++nt) {
            bf16x8 b = *(const bf16x8*)&Bs[nt * 16 + cl][lh * 8];
            acc[nt] = mfma16(a, b, acc[nt]);
        }
        __syncthreads();
    }
#pragma unroll
    for (int nt = 0; nt < 16; ++nt) {
#pragma unroll
        for (int r = 0; r < 4; ++r) {
            int rm  = rm0 + w * 16 + 4 * lh + r;
            int col = n0 + nt * 16 + cl;
            int b = rm >> 7, t = rm & 127;          // X rows are b*128+t
            size_t ro = (size_t)t * BB + b;
            if (col < 512) {
                float v = acc[nt][r] + bih[col] + bhh[col];
                *(fp16*)(gxrz2b + ro * 1024 + (col & 255) * 4 + (col >> 8) * 2) = (fp16)v;
            } else {
                gxn[ro * 256 + (col - 512)] = acc[nt][r] + bih[col];
            }
        }
    }
}

// ---------------------------------------------------------------------------
// Layers 1/2 input GEMM: same epilogue; A = Y bf16 [t*128+b][256].
// ---------------------------------------------------------------------------
__global__ __launch_bounds__(512) void gemm_gxy(const bf16* __restrict__ Y,
                                                const float* __restrict__ W,
                                                const float* __restrict__ bih,
                                                const float* __restrict__ bhh,
                                                char*  __restrict__ gxrz2b,
                                                float* __restrict__ gxn)
{
    __shared__ bf16 As[128][40];
    __shared__ bf16 Bs[256][40];
    const int tid  = threadIdx.x;
    const int lane = tid & 63;
    const int w    = tid >> 6;
    const int cl   = lane & 15;
    const int lh   = lane >> 4;
    const int rm0  = blockIdx.x * 128;
    const int n0   = blockIdx.y * 256;

    f32x4 acc[16];
#pragma unroll
    for (int i = 0; i < 16; ++i) acc[i] = (f32x4){0.f, 0.f, 0.f, 0.f};

    for (int kt = 0; kt < 8; ++kt) {
        const int k0 = kt * 32;
        {
            int row = tid >> 2;
            int c   = (tid & 3) * 8;
            *(bf16x8*)&As[row][c] =
                *(const bf16x8*)(Y + (size_t)(rm0 + row) * 256 + k0 + c);
        }
        {
            int row = tid >> 1;
            int c   = (tid & 1) * 16;
            const float* src = W + (size_t)(n0 + row) * 256 + (k0 + c);
#pragma unroll
            for (int h = 0; h < 2; ++h) {
                const float2* s2 = (const float2*)(src + h * 8);
                float2 v0 = s2[0], v1 = s2[1], v2 = s2[2], v3 = s2[3];
                bf16x8 pk;
                pk[0] = (bf16)v0.x; pk[1] = (bf16)v0.y; pk[2] = (bf16)v1.x; pk[3] = (bf16)v1.y;
                pk[4] = (bf16)v2.x; pk[5] = (bf16)v2.y; pk[6] = (bf16)v3.x; pk[7] = (bf16)v3.y;
                *(bf16x8*)&Bs[row][c + h * 8] = pk;
            }
        }
        __syncthreads();
        bf16x8 a = *(const bf16x8*)&As[w * 16 + cl][lh * 8];
#pragma unroll
        for (int nt = 0; nt < 16; ++nt) {
            bf16x8 b = *(const bf16x8*)&Bs[nt * 16 + cl][lh * 8];
            acc[nt] = mfma16(a, b, acc[nt]);
        }
        __syncthreads();
    }
#pragma unroll
    for (int nt = 0; nt < 16; ++nt) {
#pragma unroll
        for (int r = 0; r < 4; ++r) {
            size_t rm = (size_t)(rm0 + w * 16 + 4 * lh + r);   // = t*128 + b
            int col = n0 + nt * 16 + cl;
            if (col < 512) {
                float v = acc[nt][r] + bih[col] + bhh[col];
                *(fp16*)(gxrz2b + rm * 1024 + (col & 255) * 4 + (col >> 8) * 2) = (fp16)v;
            } else {
                gxn[rm * 256 + (col - 512)] = acc[nt][r] + bih[col];
            }
        }
    }
}

// ---------------------------------------------------------------------------
// Recurrent layer v3: 8 blocks x 512 threads (8 waves, 2/SIMD). Wave w owns
// col-tiles {2w, 2w+1}; 48 B-frags resident in registers. gx staged to LDS
// via global_load_lds (2-slot ring, counted vmcnt — never drained to 0);
// raw s_barrier with lgkm-only drains; vectorized Y epilogue.
// ---------------------------------------------------------------------------
__global__ __launch_bounds__(512, 2) void gru_rec(
    const unsigned int* __restrict__ grzp,  // [T*B][256] dwords: (fp16 r, fp16 z)
    const float* __restrict__ gxn,          // [T*B][256] fp32 (n, incl b_ih)
    const bf16*  __restrict__ Wh,           // this layer's hh pack
    const float* __restrict__ bhh,          // raw b_hh (768); only n-part used
    const float* __restrict__ h0,           // hidden + l*128*256
    bf16*  __restrict__ Y,                  // [T*B][256] bf16 out (always valid)
    float* __restrict__ hnfL)               // hnf + l*256 (stride 768)
{
    __shared__ bf16 Ah[16][264];
    __shared__ __align__(16) char gxl[2][2][16][1040];  // [slot][rz|n][row][1KB+16 pad]

    const int tid  = threadIdx.x;
    const int lane = tid & 63;
    const int w    = tid >> 6;              // 0..7
    const int cl   = lane & 15;
    const int lh   = lane >> 4;
    const int g    = blockIdx.x;

    // ---- 48 B-fragments -> registers ----
    bf16x8 Br[2][8], Bz[2][8], Bn[2][8];
#pragma unroll
    for (int ji = 0; ji < 2; ++ji) {
        const int jt = 2 * w + ji;
#pragma unroll
        for (int kk = 0; kk < 8; ++kk) {
            Br[ji][kk] = *(const bf16x8*)(Wh + (size_t)(( jt       * 8 + kk) * 512) + lane * 8);
            Bz[ji][kk] = *(const bf16x8*)(Wh + (size_t)(((16 + jt) * 8 + kk) * 512) + lane * 8);
            Bn[ji][kk] = *(const bf16x8*)(Wh + (size_t)(((32 + jt) * 8 + kk) * 512) + lane * 8);
        }
    }
    float bN[2];
#pragma unroll
    for (int ji = 0; ji < 2; ++ji)
        bN[ji] = bhh[512 + (2 * w + ji) * 16 + cl];

    // gx tile stage: wave w stages rows {2w, 2w+1} of both planes (DMA, 16B/lane)
    auto STAGE = [&](int tt, int slot) {
#pragma unroll
        for (int i = 0; i < 2; ++i) {
            const int row = 2 * w + i;
            const size_t gr = (size_t)tt * BB + g * 16 + row;
            const unsigned int* s0 = grzp + gr * 256 + lane * 4;
            const float*        s1 = gxn  + gr * 256 + lane * 4;
            __builtin_amdgcn_global_load_lds(
                (const __attribute__((address_space(1))) void*)s0,
                (__attribute__((address_space(3))) void*)&gxl[slot][0][row][0], 16, 0, 0);
            __builtin_amdgcn_global_load_lds(
                (const __attribute__((address_space(1))) void*)s1,
                (__attribute__((address_space(3))) void*)&gxl[slot][1][row][0], 16, 0, 0);
        }
    };

    // ---- prologue: h0 -> regs + Ah; issue tile 0 ----
    float hprev[2][4];
#pragma unroll
    for (int ji = 0; ji < 2; ++ji) {
        const int col = (2 * w + ji) * 16 + cl;
#pragma unroll
        for (int r = 0; r < 4; ++r) {
            const int m = 4 * lh + r;
            float v = h0[(size_t)(g * 16 + m) * 256 + col];
            hprev[ji][r] = v;
            Ah[m][col] = (bf16)v;
        }
    }
    STAGE(0, 0);
    __syncthreads();   // one-time full drain (tile 0 + Ah staged)

    for (int t = 0; t < TT; ++t) {
        const int slot = t & 1;
        // ---- phase 1: issue next tile, MFMA over Ah ----
        STAGE((t + 1 < TT) ? t + 1 : TT - 1, slot ^ 1);
        f32x4 cr[2], cz[2], cn[2];
#pragma unroll
        for (int i = 0; i < 2; ++i) {
            cr[i] = (f32x4){0.f,0.f,0.f,0.f};
            cz[i] = (f32x4){0.f,0.f,0.f,0.f};
            cn[i] = (f32x4){0.f,0.f,0.f,0.f};
        }
#pragma unroll
        for (int kk = 0; kk < 8; ++kk) {
            bf16x8 a = *(const bf16x8*)&Ah[cl][kk * 32 + lh * 8];
#pragma unroll
            for (int ji = 0; ji < 2; ++ji) {
                cr[ji] = mfma16(a, Br[ji][kk], cr[ji]);
                cz[ji] = mfma16(a, Bz[ji][kk], cz[ji]);
                cn[ji] = mfma16(a, Bn[ji][kk], cn[ji]);
            }
        }
        asm volatile("s_waitcnt lgkmcnt(0)" ::: "memory");
        __builtin_amdgcn_sched_barrier(0);
        __builtin_amdgcn_s_barrier();          // A: all Ah reads done
        __builtin_amdgcn_sched_barrier(0);

        // ---- tile t ready? (newer ops: 1 Y-store + 4 next-tile loads) ----
        if (t == 0) asm volatile("s_waitcnt vmcnt(4)" ::: "memory");
        else        asm volatile("s_waitcnt vmcnt(5)" ::: "memory");
        __builtin_amdgcn_sched_barrier(0);

        // ---- gates: gx from LDS, h update, Ah write ----
#pragma unroll
        for (int ji = 0; ji < 2; ++ji) {
            const int col = (2 * w + ji) * 16 + cl;
#pragma unroll
            for (int r = 0; r < 4; ++r) {
                const int m = 4 * lh + r;
                unsigned int rzu = *(const unsigned int*)&gxl[slot][0][m][col * 4];
                float gnv        = *(const float*)       &gxl[slot][1][m][col * 4];
                fp16x2 rz = __builtin_bit_cast(fp16x2, rzu);
                float rr_ = sigf((float)rz[0] + cr[ji][r]);
                float zz  = sigf((float)rz[1] + cz[ji][r]);
                float nn  = tanhfast(gnv + rr_ * (cn[ji][r] + bN[ji]));
                float hnew = (1.f - zz) * nn + zz * hprev[ji][r];
                hprev[ji][r] = hnew;
                Ah[m][col] = (bf16)hnew;
                if (t == TT - 1) hnfL[(size_t)(g * 16 + m) * 768 + col] = hnew;
            }
        }
        asm volatile("s_waitcnt lgkmcnt(0)" ::: "memory");
        __builtin_amdgcn_sched_barrier(0);
        __builtin_amdgcn_s_barrier();          // B: Ah writes visible
        __builtin_amdgcn_sched_barrier(0);

        // ---- vectorized Y epilogue (store stays in flight) ----
        {
            const int yrow = tid >> 5;          // 0..15
            const int yc   = (tid & 31) * 8;    // 0..248
            bf16x8 yv = *(const bf16x8*)&Ah[yrow][yc];
            *(bf16x8*)(Y + ((size_t)t * BB + g * 16 + yrow) * 256 + yc) = yv;
        }
    }
}

// ---------------------------------------------------------------------------
__global__ __launch_bounds__(256) void fc_out(const float* __restrict__ hn,
                                              const float* __restrict__ fcw,
                                              const float* __restrict__ fcb,
                                              float* __restrict__ out)
{
    __shared__ float hs[768];
    const int b = blockIdx.x;
    for (int i = threadIdx.x; i < 768; i += 256) hs[i] = hn[(size_t)b * 768 + i];
    __syncthreads();
    for (int i = threadIdx.x; i < H_IN; i += 256) {
        const float4* wr = (const float4*)(fcw + (size_t)i * 768);
        float a0 = 0.f, a1 = 0.f, a2 = 0.f, a3 = 0.f;
#pragma unroll 4
        for (int c = 0; c < 192; ++c) {
            float4 wv = wr[c];
            const float* h4 = &hs[c * 4];
            a0 += wv.x * h4[0]; a1 += wv.y * h4[1];
            a2 += wv.z * h4[2]; a3 += wv.w * h4[3];
        }
        out[(size_t)b * H_IN + i] = fcb[i] + a0 + a1 + a2 + a3;
    }
}

extern "C" void kernel_launch(void* const* d_in, const int* in_sizes, int n_in,
                              void* d_out, int out_size, void* d_ws, size_t ws_size,
                              hipStream_t stream) {
    const float* X    = (const float*)d_in[0];
    const float* hid  = (const float*)d_in[1];
    const float* wih0 = (const float*)d_in[2];
    const float* whh0 = (const float*)d_in[3];
    const float* bih0 = (const float*)d_in[4];
    const float* bhh0 = (const float*)d_in[5];
    const float* wih1 = (const float*)d_in[6];
    const float* whh1 = (const float*)d_in[7];
    const float* bih1 = (const float*)d_in[8];
    const float* bhh1 = (const float*)d_in[9];
    const float* wih2 = (const float*)d_in[10];
    const float* whh2 = (const float*)d_in[11];
    const float* bih2 = (const float*)d_in[12];
    const float* bhh2 = (const float*)d_in[13];
    const float* fcw  = (const float*)d_in[14];
    const float* fcb  = (const float*)d_in[15];
    float* out = (float*)d_out;

    // Layout (total 43,525,120 B — within the known-safe 52.7 MB):
    char* ws = (char*)d_ws;
    bf16*  Wh    = (bf16*)ws;                      //          0 .. 1,179,648
    float* hnf   = (float*)(ws + 1188864);         //  1,188,864 .. 1,582,080
    bf16*  Y     = (bf16*)(ws + 1582080);          //  1,582,080 .. 9,970,688
    float* gxn   = (float*)(ws + 9970688);         //  9,970,688 .. 26,747,904
    char*  gxrzb = ws + 26747904;                  // 26,747,904 .. 43,525,120
    const unsigned int* grzp = (const unsigned int*)gxrzb;

    prep_pack2<<<dim3(1152), dim3(512), 0, stream>>>(whh0, whh1, whh2, Wh);
    // layer 0
    gemm_gx0<<<dim3(128, 3), dim3(512), 0, stream>>>(X, wih0, bih0, bhh0, gxrzb, gxn);
    gru_rec<<<dim3(8), dim3(512), 0, stream>>>(grzp, gxn, Wh, bhh0,
                                               hid, Y, hnf);
    // layer 1
    gemm_gxy<<<dim3(128, 3), dim3(512), 0, stream>>>(Y, wih1, bih1, bhh1, gxrzb, gxn);
    gru_rec<<<dim3(8), dim3(512), 0, stream>>>(grzp, gxn, Wh + 196608, bhh1,
                                               hid + 32768, Y, hnf + 256);
    // layer 2
    gemm_gxy<<<dim3(128, 3), dim3(512), 0, stream>>>(Y, wih2, bih2, bhh2, gxrzb, gxn);
    gru_rec<<<dim3(8), dim3(512), 0, stream>>>(grzp, gxn, Wh + 393216, bhh2,
                                               hid + 65536, Y, hnf + 512);
    // head
    fc_out<<<dim3(128), dim3(256), 0, stream>>>(hnf, fcw, fcb, out);
    hipMemcpyAsync(out + 171776, hid, 98304 * sizeof(float),
                   hipMemcpyDeviceToDevice, stream);
}

// Round 9
// 1752.533 us; speedup vs baseline: 1.3575x; 1.0327x over previous
//
#include <hip/hip_runtime.h>
#include <hip/hip_bf16.h>

typedef __bf16 bf16;
typedef _Float16 fp16;
typedef __attribute__((ext_vector_type(8))) __bf16 bf16x8;
typedef __attribute__((ext_vector_type(2))) _Float16 fp16x2;
typedef __attribute__((ext_vector_type(4))) float f32x4;

#define H_IN 1342
#define TT   128
#define BB   128

static __device__ __forceinline__ f32x4 mfma16(bf16x8 a, bf16x8 b, f32x4 c) {
    return __builtin_amdgcn_mfma_f32_16x16x32_bf16(a, b, c, 0, 0, 0);
}
static __device__ __forceinline__ float sigf(float x) {
    return 1.f / (1.f + __expf(-x));
}
static __device__ __forceinline__ float tanhfast(float x) {
    return 2.f / (1.f + __expf(-2.f * x)) - 1.f;
}

// ---------------------------------------------------------------------------
// Pack the three w_hh matrices (768x256) into MFMA B-fragment order.
// (round-6 verified)
// ---------------------------------------------------------------------------
__global__ void prep_pack2(const float* __restrict__ whh0,
                           const float* __restrict__ whh1,
                           const float* __restrict__ whh2,
                           bf16* __restrict__ Wh)
{
    int idx = blockIdx.x * blockDim.x + threadIdx.x;
    if (idx < 589824) {
        int l = idx / 196608;
        int r = idx - l * 196608;
        const float* w = (l == 0) ? whh0 : (l == 1) ? whh1 : whh2;
        int f = r >> 9, q = r & 511;
        int lane = q >> 3, j = q & 7;
        int nt = f >> 3, kt = f & 7;
        int n = nt * 16 + (lane & 15);
        int k = kt * 32 + (lane >> 4) * 8 + j;
        Wh[idx] = (bf16)w[n * 256 + k];
    }
}

// ---------------------------------------------------------------------------
// Layer-0 input GEMM. Epilogue: r,z -> interleaved fp16x2 dword plane
// (lo=r, hi=z, b_hh folded), n -> fp32 plane. (round-6/7/8 verified)
// ---------------------------------------------------------------------------
__global__ __launch_bounds__(512) void gemm_gx0(const float* __restrict__ X,
                                                const float* __restrict__ W,
                                                const float* __restrict__ bih,
                                                const float* __restrict__ bhh,
                                                char*  __restrict__ gxrz2b,
                                                float* __restrict__ gxn)
{
    __shared__ bf16 As[128][40];
    __shared__ bf16 Bs[256][40];
    const int tid  = threadIdx.x;
    const int lane = tid & 63;
    const int w    = tid >> 6;
    const int cl   = lane & 15;
    const int lh   = lane >> 4;
    const int rm0  = blockIdx.x * 128;
    const int n0   = blockIdx.y * 256;

    f32x4 acc[16];
#pragma unroll
    for (int i = 0; i < 16; ++i) acc[i] = (f32x4){0.f, 0.f, 0.f, 0.f};

    for (int kt = 0; kt < 42; ++kt) {
        const int k0 = kt * 32;
        {
            int row = tid >> 2;
            int c   = (tid & 3) * 8;
            const float* src = X + (size_t)(rm0 + row) * H_IN + (k0 + c);
            bf16x8 pk;
            if (k0 + c + 8 <= H_IN) {
                const float2* s2 = (const float2*)src;
                float2 v0 = s2[0], v1 = s2[1], v2 = s2[2], v3 = s2[3];
                pk[0] = (bf16)v0.x; pk[1] = (bf16)v0.y; pk[2] = (bf16)v1.x; pk[3] = (bf16)v1.y;
                pk[4] = (bf16)v2.x; pk[5] = (bf16)v2.y; pk[6] = (bf16)v3.x; pk[7] = (bf16)v3.y;
            } else {
#pragma unroll
                for (int i = 0; i < 8; ++i)
                    pk[i] = (bf16)((k0 + c + i < H_IN) ? src[i] : 0.f);
            }
            *(bf16x8*)&As[row][c] = pk;
        }
        {
            int row = tid >> 1;
            int c   = (tid & 1) * 16;
            const float* src = W + (size_t)(n0 + row) * H_IN + (k0 + c);
#pragma unroll
            for (int h = 0; h < 2; ++h) {
                const float* s = src + h * 8;
                bf16x8 pk;
                if (k0 + c + h * 8 + 8 <= H_IN) {
                    const float2* s2 = (const float2*)s;
                    float2 v0 = s2[0], v1 = s2[1], v2 = s2[2], v3 = s2[3];
                    pk[0] = (bf16)v0.x; pk[1] = (bf16)v0.y; pk[2] = (bf16)v1.x; pk[3] = (bf16)v1.y;
                    pk[4] = (bf16)v2.x; pk[5] = (bf16)v2.y; pk[6] = (bf16)v3.x; pk[7] = (bf16)v3.y;
                } else {
#pragma unroll
                    for (int i = 0; i < 8; ++i)
                        pk[i] = (bf16)((k0 + c + h * 8 + i < H_IN) ? s[i] : 0.f);
                }
                *(bf16x8*)&Bs[row][c + h * 8] = pk;
            }
        }
        __syncthreads();
        bf16x8 a = *(const bf16x8*)&As[w * 16 + cl][lh * 8];
#pragma unroll
        for (int nt = 0; nt < 16; ++nt) {
            bf16x8 b = *(const bf16x8*)&Bs[nt * 16 + cl][lh * 8];
            acc[nt] = mfma16(a, b, acc[nt]);
        }
        __syncthreads();
    }
#pragma unroll
    for (int nt = 0; nt < 16; ++nt) {
#pragma unroll
        for (int r = 0; r < 4; ++r) {
            int rm  = rm0 + w * 16 + 4 * lh + r;
            int col = n0 + nt * 16 + cl;
            int b = rm >> 7, t = rm & 127;          // X rows are b*128+t
            size_t ro = (size_t)t * BB + b;
            if (col < 512) {
                float v = acc[nt][r] + bih[col] + bhh[col];
                *(fp16*)(gxrz2b + ro * 1024 + (col & 255) * 4 + (col >> 8) * 2) = (fp16)v;
            } else {
                gxn[ro * 256 + (col - 512)] = acc[nt][r] + bih[col];
            }
        }
    }
}

// ---------------------------------------------------------------------------
// Layers 1/2 input GEMM: same epilogue; A = Y bf16 [t*128+b][256].
// ---------------------------------------------------------------------------
__global__ __launch_bounds__(512) void gemm_gxy(const bf16* __restrict__ Y,
                                                const float* __restrict__ W,
                                                const float* __restrict__ bih,
                                                const float* __restrict__ bhh,
                                                char*  __restrict__ gxrz2b,
                                                float* __restrict__ gxn)
{
    __shared__ bf16 As[128][40];
    __shared__ bf16 Bs[256][40];
    const int tid  = threadIdx.x;
    const int lane = tid & 63;
    const int w    = tid >> 6;
    const int cl   = lane & 15;
    const int lh   = lane >> 4;
    const int rm0  = blockIdx.x * 128;
    const int n0   = blockIdx.y * 256;

    f32x4 acc[16];
#pragma unroll
    for (int i = 0; i < 16; ++i) acc[i] = (f32x4){0.f, 0.f, 0.f, 0.f};

    for (int kt = 0; kt < 8; ++kt) {
        const int k0 = kt * 32;
        {
            int row = tid >> 2;
            int c   = (tid & 3) * 8;
            *(bf16x8*)&As[row][c] =
                *(const bf16x8*)(Y + (size_t)(rm0 + row) * 256 + k0 + c);
        }
        {
            int row = tid >> 1;
            int c   = (tid & 1) * 16;
            const float* src = W + (size_t)(n0 + row) * 256 + (k0 + c);
#pragma unroll
            for (int h = 0; h < 2; ++h) {
                const float2* s2 = (const float2*)(src + h * 8);
                float2 v0 = s2[0], v1 = s2[1], v2 = s2[2], v3 = s2[3];
                bf16x8 pk;
                pk[0] = (bf16)v0.x; pk[1] = (bf16)v0.y; pk[2] = (bf16)v1.x; pk[3] = (bf16)v1.y;
                pk[4] = (bf16)v2.x; pk[5] = (bf16)v2.y; pk[6] = (bf16)v3.x; pk[7] = (bf16)v3.y;
                *(bf16x8*)&Bs[row][c + h * 8] = pk;
            }
        }
        __syncthreads();
        bf16x8 a = *(const bf16x8*)&As[w * 16 + cl][lh * 8];
#pragma unroll
        for (int nt = 0; nt < 16; ++nt) {
            bf16x8 b = *(const bf16x8*)&Bs[nt * 16 + cl][lh * 8];
            acc[nt] = mfma16(a, b, acc[nt]);
        }
        __syncthreads();
    }
#pragma unroll
    for (int nt = 0; nt < 16; ++nt) {
#pragma unroll
        for (int r = 0; r < 4; ++r) {
            size_t rm = (size_t)(rm0 + w * 16 + 4 * lh + r);   // = t*128 + b
            int col = n0 + nt * 16 + cl;
            if (col < 512) {
                float v = acc[nt][r] + bih[col] + bhh[col];
                *(fp16*)(gxrz2b + rm * 1024 + (col & 255) * 4 + (col >> 8) * 2) = (fp16)v;
            } else {
                gxn[rm * 256 + (col - 512)] = acc[nt][r] + bih[col];
            }
        }
    }
}

// ---------------------------------------------------------------------------
// Recurrent layer v4 = round-8 v3 + register-pinned weights.
// 8 blocks x 512 threads (8 waves, 1 block/CU, 2 waves/SIMD). Wave w owns
// col-tiles {2w, 2w+1}; 48 B-frags PINNED in VGPRs via empty asm (+v) so the
// compiler cannot rematerialize them from L2 inside the t-loop.
// ---------------------------------------------------------------------------
__global__ __launch_bounds__(512, 2) void gru_rec(
    const unsigned int* __restrict__ grzp,  // [T*B][256] dwords: (fp16 r, fp16 z)
    const float* __restrict__ gxn,          // [T*B][256] fp32 (n, incl b_ih)
    const bf16*  __restrict__ Wh,           // this layer's hh pack
    const float* __restrict__ bhh,          // raw b_hh (768); only n-part used
    const float* __restrict__ h0,           // hidden + l*128*256
    bf16*  __restrict__ Y,                  // [T*B][256] bf16 out
    float* __restrict__ hnfL)               // hnf + l*256 (stride 768)
{
    __shared__ bf16 Ah[16][264];
    __shared__ __align__(16) char gxl[2][2][16][1040];  // [slot][rz|n][row][1KB+16 pad]

    const int tid  = threadIdx.x;
    const int lane = tid & 63;
    const int w    = tid >> 6;              // 0..7
    const int cl   = lane & 15;
    const int lh   = lane >> 4;
    const int g    = blockIdx.x;

    // ---- 48 B-fragments -> registers, PINNED ----
    bf16x8 Br[2][8], Bz[2][8], Bn[2][8];
#pragma unroll
    for (int ji = 0; ji < 2; ++ji) {
        const int jt = 2 * w + ji;
#pragma unroll
        for (int kk = 0; kk < 8; ++kk) {
            Br[ji][kk] = *(const bf16x8*)(Wh + (size_t)(( jt       * 8 + kk) * 512) + lane * 8);
            Bz[ji][kk] = *(const bf16x8*)(Wh + (size_t)(((16 + jt) * 8 + kk) * 512) + lane * 8);
            Bn[ji][kk] = *(const bf16x8*)(Wh + (size_t)(((32 + jt) * 8 + kk) * 512) + lane * 8);
        }
    }
#pragma unroll
    for (int ji = 0; ji < 2; ++ji)
#pragma unroll
        for (int kk = 0; kk < 8; ++kk) {
            asm volatile("" : "+v"(Br[ji][kk]));
            asm volatile("" : "+v"(Bz[ji][kk]));
            asm volatile("" : "+v"(Bn[ji][kk]));
        }
    float bN[2];
#pragma unroll
    for (int ji = 0; ji < 2; ++ji)
        bN[ji] = bhh[512 + (2 * w + ji) * 16 + cl];

    // gx tile stage: wave w stages rows {2w, 2w+1} of both planes (DMA, 16B/lane)
    auto STAGE = [&](int tt, int slot) {
#pragma unroll
        for (int i = 0; i < 2; ++i) {
            const int row = 2 * w + i;
            const size_t gr = (size_t)tt * BB + g * 16 + row;
            const unsigned int* s0 = grzp + gr * 256 + lane * 4;
            const float*        s1 = gxn  + gr * 256 + lane * 4;
            __builtin_amdgcn_global_load_lds(
                (const __attribute__((address_space(1))) void*)s0,
                (__attribute__((address_space(3))) void*)&gxl[slot][0][row][0], 16, 0, 0);
            __builtin_amdgcn_global_load_lds(
                (const __attribute__((address_space(1))) void*)s1,
                (__attribute__((address_space(3))) void*)&gxl[slot][1][row][0], 16, 0, 0);
        }
    };

    // ---- prologue: h0 -> regs + Ah; issue tile 0 ----
    float hprev[2][4];
#pragma unroll
    for (int ji = 0; ji < 2; ++ji) {
        const int col = (2 * w + ji) * 16 + cl;
#pragma unroll
        for (int r = 0; r < 4; ++r) {
            const int m = 4 * lh + r;
            float v = h0[(size_t)(g * 16 + m) * 256 + col];
            hprev[ji][r] = v;
            Ah[m][col] = (bf16)v;
        }
    }
    STAGE(0, 0);
    __syncthreads();   // one-time full drain (tile 0 + Ah staged)

    for (int t = 0; t < TT; ++t) {
        const int slot = t & 1;
        // ---- phase 1: issue next tile, MFMA over Ah ----
        STAGE((t + 1 < TT) ? t + 1 : TT - 1, slot ^ 1);
        f32x4 cr[2], cz[2], cn[2];
#pragma unroll
        for (int i = 0; i < 2; ++i) {
            cr[i] = (f32x4){0.f,0.f,0.f,0.f};
            cz[i] = (f32x4){0.f,0.f,0.f,0.f};
            cn[i] = (f32x4){0.f,0.f,0.f,0.f};
        }
#pragma unroll
        for (int kk = 0; kk < 8; ++kk) {
            bf16x8 a = *(const bf16x8*)&Ah[cl][kk * 32 + lh * 8];
#pragma unroll
            for (int ji = 0; ji < 2; ++ji) {
                cr[ji] = mfma16(a, Br[ji][kk], cr[ji]);
                cz[ji] = mfma16(a, Bz[ji][kk], cz[ji]);
                cn[ji] = mfma16(a, Bn[ji][kk], cn[ji]);
            }
        }
        asm volatile("s_waitcnt lgkmcnt(0)" ::: "memory");
        __builtin_amdgcn_sched_barrier(0);
        __builtin_amdgcn_s_barrier();          // A: all Ah reads done
        __builtin_amdgcn_sched_barrier(0);

        // ---- tile t ready? (newer ops: 1 Y-store + 4 next-tile loads) ----
        if (t == 0) asm volatile("s_waitcnt vmcnt(4)" ::: "memory");
        else        asm volatile("s_waitcnt vmcnt(5)" ::: "memory");
        __builtin_amdgcn_sched_barrier(0);

        // ---- gates: gx from LDS, h update, Ah write ----
#pragma unroll
        for (int ji = 0; ji < 2; ++ji) {
            const int col = (2 * w + ji) * 16 + cl;
#pragma unroll
            for (int r = 0; r < 4; ++r) {
                const int m = 4 * lh + r;
                unsigned int rzu = *(const unsigned int*)&gxl[slot][0][m][col * 4];
                float gnv        = *(const float*)       &gxl[slot][1][m][col * 4];
                fp16x2 rz = __builtin_bit_cast(fp16x2, rzu);
                float rr_ = sigf((float)rz[0] + cr[ji][r]);
                float zz  = sigf((float)rz[1] + cz[ji][r]);
                float nn  = tanhfast(gnv + rr_ * (cn[ji][r] + bN[ji]));
                float hnew = (1.f - zz) * nn + zz * hprev[ji][r];
                hprev[ji][r] = hnew;
                Ah[m][col] = (bf16)hnew;
                if (t == TT - 1) hnfL[(size_t)(g * 16 + m) * 768 + col] = hnew;
            }
        }
        asm volatile("s_waitcnt lgkmcnt(0)" ::: "memory");
        __builtin_amdgcn_sched_barrier(0);
        __builtin_amdgcn_s_barrier();          // B: Ah writes visible
        __builtin_amdgcn_sched_barrier(0);

        // ---- vectorized Y epilogue (store stays in flight) ----
        {
            const int yrow = tid >> 5;          // 0..15
            const int yc   = (tid & 31) * 8;    // 0..248
            bf16x8 yv = *(const bf16x8*)&Ah[yrow][yc];
            *(bf16x8*)(Y + ((size_t)t * BB + g * 16 + yrow) * 256 + yc) = yv;
        }
    }
}

// ---------------------------------------------------------------------------
__global__ __launch_bounds__(256) void fc_out(const float* __restrict__ hn,
                                              const float* __restrict__ fcw,
                                              const float* __restrict__ fcb,
                                              float* __restrict__ out)
{
    __shared__ float hs[768];
    const int b = blockIdx.x;
    for (int i = threadIdx.x; i < 768; i += 256) hs[i] = hn[(size_t)b * 768 + i];
    __syncthreads();
    for (int i = threadIdx.x; i < H_IN; i += 256) {
        const float4* wr = (const float4*)(fcw + (size_t)i * 768);
        float a0 = 0.f, a1 = 0.f, a2 = 0.f, a3 = 0.f;
#pragma unroll 4
        for (int c = 0; c < 192; ++c) {
            float4 wv = wr[c];
            const float* h4 = &hs[c * 4];
            a0 += wv.x * h4[0]; a1 += wv.y * h4[1];
            a2 += wv.z * h4[2]; a3 += wv.w * h4[3];
        }
        out[(size_t)b * H_IN + i] = fcb[i] + a0 + a1 + a2 + a3;
    }
}

extern "C" void kernel_launch(void* const* d_in, const int* in_sizes, int n_in,
                              void* d_out, int out_size, void* d_ws, size_t ws_size,
                              hipStream_t stream) {
    const float* X    = (const float*)d_in[0];
    const float* hid  = (const float*)d_in[1];
    const float* wih0 = (const float*)d_in[2];
    const float* whh0 = (const float*)d_in[3];
    const float* bih0 = (const float*)d_in[4];
    const float* bhh0 = (const float*)d_in[5];
    const float* wih1 = (const float*)d_in[6];
    const float* whh1 = (const float*)d_in[7];
    const float* bih1 = (const float*)d_in[8];
    const float* bhh1 = (const float*)d_in[9];
    const float* wih2 = (const float*)d_in[10];
    const float* whh2 = (const float*)d_in[11];
    const float* bih2 = (const float*)d_in[12];
    const float* bhh2 = (const float*)d_in[13];
    const float* fcw  = (const float*)d_in[14];
    const float* fcb  = (const float*)d_in[15];
    float* out = (float*)d_out;

    // Layout (total 43,525,120 B — within the known-safe 52.7 MB):
    char* ws = (char*)d_ws;
    bf16*  Wh    = (bf16*)ws;                      //          0 .. 1,179,648
    float* hnf   = (float*)(ws + 1188864);         //  1,188,864 .. 1,582,080
    bf16*  Y     = (bf16*)(ws + 1582080);          //  1,582,080 .. 9,970,688
    float* gxn   = (float*)(ws + 9970688);         //  9,970,688 .. 26,747,904
    char*  gxrzb = ws + 26747904;                  // 26,747,904 .. 43,525,120
    const unsigned int* grzp = (const unsigned int*)gxrzb;

    prep_pack2<<<dim3(1152), dim3(512), 0, stream>>>(whh0, whh1, whh2, Wh);
    // layer 0
    gemm_gx0<<<dim3(128, 3), dim3(512), 0, stream>>>(X, wih0, bih0, bhh0, gxrzb, gxn);
    gru_rec<<<dim3(8), dim3(512), 0, stream>>>(grzp, gxn, Wh, bhh0,
                                               hid, Y, hnf);
    // layer 1
    gemm_gxy<<<dim3(128, 3), dim3(512), 0, stream>>>(Y, wih1, bih1, bhh1, gxrzb, gxn);
    gru_rec<<<dim3(8), dim3(512), 0, stream>>>(grzp, gxn, Wh + 196608, bhh1,
                                               hid + 32768, Y, hnf + 256);
    // layer 2
    gemm_gxy<<<dim3(128, 3), dim3(512), 0, stream>>>(Y, wih2, bih2, bhh2, gxrzb, gxn);
    gru_rec<<<dim3(8), dim3(512), 0, stream>>>(grzp, gxn, Wh + 393216, bhh2,
                                               hid + 65536, Y, hnf + 512);
    // head
    fc_out<<<dim3(128), dim3(256), 0, stream>>>(hnf, fcw, fcb, out);
    hipMemcpyAsync(out + 171776, hid, 98304 * sizeof(float),
                   hipMemcpyDeviceToDevice, stream);
}